// Round 2
// baseline (170.810 us; speedup 1.0000x reference)
//
#include <hip/hip_runtime.h>

// SLAYER 2-layer SNN, MI355X. Round-2: row-LUT binary convolution.
// Layer pipeline (psp commutes with conv; convs see BINARY spike trains):
//   K1: conv1(5x5) via per-row 5-bit-pattern LUT + psp1 + lif1 -> packed s1 bits (d_ws)
//   K2: conv2(3x3) via per-row 3-bit-pattern LUT + psp2 + lif2 -> float output
// Bit layout: rowT[row][t] = uint32, bit c = spike at column (x0 - pad + c) at time t.
// Per output px per t: conv = R x (LDS word read, shift/mask, LDS LUT read, add).
// Scan (psp+LIF) arithmetic is kept operation-for-operation identical to the
// round-0 kernel, which matched the reference exactly (absmax = 0).

#define HH   192
#define WW   192
#define NIMG 4
#define TT   64
#define TILE 16
#define NT   256
#define R1   20   // TILE+4 input rows/cols for conv1 (x0-2 .. x0+17)
#define R2   18   // TILE+2 s1 rows/cols for conv2  (x0-1 .. x0+16)
#define TP   65   // padded t-stride for rowT words (bank-conflict break)

#define E_D 2.718281828459045
static constexpr float D1  = (float)0.36787944117144233;   // exp(-1/1)
static constexpr float CP1 = (float)(E_D);
static constexpr float DR1 = (float)0.36787944117144233;
static constexpr float CR1 = (float)(-30.0 * E_D);
static constexpr float D2  = (float)0.6065306597126334;    // exp(-1/2)
static constexpr float CP2 = (float)(E_D * 0.5);
static constexpr float DR2 = (float)0.6065306597126334;
static constexpr float CR2 = (float)(-50.0 * E_D * 0.5);
static constexpr float TH1 = 30.0f;
static constexpr float TH2 = 50.0f;

// ---------------- K1: conv1 (LUT) + psp1 + lif1 -> s1 packed bits ----------
__global__ __launch_bounds__(NT)
void k1_conv_lif(const float* __restrict__ in, const float* __restrict__ w1g,
                 uint2* __restrict__ s1b) {
    __shared__ float    lut[5 * 32];
    __shared__ unsigned rowT[R1 * TP];

    const int n = blockIdx.z, y0 = blockIdx.y * TILE, x0 = blockIdx.x * TILE;
    const int tid = threadIdx.x;

    // LUT: lut[r*32+p] = sum_j w1[r][j] * bit_j(p)   (exact f32, deterministic)
    if (tid < 160) {
        const int r = tid >> 5, p = tid & 31;
        float s = 0.f;
#pragma unroll
        for (int j = 0; j < 5; j++)
            if ((p >> j) & 1) s += w1g[r * 5 + j];
        lut[tid] = s;
    }

    // rowT build: lanes = t, wave handles every 4th row. Coalesced 256B loads.
    const int wv = tid >> 6, ln = tid & 63;
    for (int r = wv; r < R1; r += 4) {
        const int gy = y0 - 2 + r;
        unsigned word = 0u;
        if (gy >= 0 && gy < HH) {
            const float* rowp = in + (((size_t)n * HH + gy) * WW) * TT + ln;
#pragma unroll
            for (int c = 0; c < R1; c++) {
                const int gx = x0 - 2 + c;
                if (gx >= 0 && gx < WW) {
                    float v = rowp[(size_t)gx * TT];
                    word |= (v != 0.f) ? (1u << c) : 0u;
                }
            }
        }
        rowT[r * TP + ln] = word;
    }
    __syncthreads();

    // fused conv + scan, lane = px (row = tid/16, col = tid%16)
    const int row = tid >> 4, col = tid & 15;
    float u1 = 0.f, v1 = 0.f, ur = 0.f, vr = 0.f;
    unsigned slo = 0u, shi = 0u;

#pragma unroll
    for (int t = 0; t < 32; t++) {
        float c = 0.f;
#pragma unroll
        for (int i = 0; i < 5; i++) {
            const unsigned w = rowT[(row + i) * TP + t];
            c += lut[i * 32 + ((w >> col) & 31)];
        }
        v1 = D1 * (v1 + u1);
        float p = CP1 * v1;
        u1 = D1 * u1 + c;
        vr = DR1 * (vr + ur);
        float m = p + CR1 * vr;
        bool sp = (m >= TH1);
        ur = DR1 * ur + (sp ? 1.f : 0.f);
        slo |= sp ? (1u << t) : 0u;
    }
#pragma unroll
    for (int t = 0; t < 32; t++) {
        float c = 0.f;
#pragma unroll
        for (int i = 0; i < 5; i++) {
            const unsigned w = rowT[(row + i) * TP + (t + 32)];
            c += lut[i * 32 + ((w >> col) & 31)];
        }
        v1 = D1 * (v1 + u1);
        float p = CP1 * v1;
        u1 = D1 * u1 + c;
        vr = DR1 * (vr + ur);
        float m = p + CR1 * vr;
        bool sp = (m >= TH1);
        ur = DR1 * ur + (sp ? 1.f : 0.f);
        shi |= sp ? (1u << t) : 0u;
    }
    s1b[((size_t)n * HH + (y0 + row)) * WW + (x0 + col)] = make_uint2(slo, shi);
}

// ---------------- K2: conv2 (LUT) + psp2 + lif2 -> float spikes ------------
__global__ __launch_bounds__(NT)
void k2_conv_lif_out(const uint2* __restrict__ s1b, const float* __restrict__ w2g,
                     float* __restrict__ out) {
    __shared__ float    lut[3 * 8];
    __shared__ unsigned rowT[R2 * TP];
    __shared__ uint2    s2b[NT];

    const int n = blockIdx.z, y0 = blockIdx.y * TILE, x0 = blockIdx.x * TILE;
    const int tid = threadIdx.x;

    if (tid < 24) {
        const int r = tid >> 3, p = tid & 7;
        float s = 0.f;
#pragma unroll
        for (int j = 0; j < 3; j++)
            if ((p >> j) & 1) s += w2g[r * 3 + j];
        lut[tid] = s;
    }

    // rowT2 build from packed s1 bits: lanes = t, per-col words are wave-uniform.
    const int wv = tid >> 6, ln = tid & 63;
    for (int r = wv; r < R2; r += 4) {
        const int gy = y0 - 1 + r;
        unsigned word = 0u;
        if (gy >= 0 && gy < HH) {
            const uint2* rp = s1b + ((size_t)n * HH + gy) * WW;
#pragma unroll
            for (int c = 0; c < R2; c++) {
                const int gx = x0 - 1 + c;
                if (gx >= 0 && gx < WW) {
                    const uint2 b = rp[gx];                 // uniform -> scalar load
                    const unsigned w = (ln < 32) ? b.x : b.y;
                    word |= ((w >> (ln & 31)) & 1u) << c;
                }
            }
        }
        rowT[r * TP + ln] = word;
    }
    __syncthreads();

    const int row = tid >> 4, col = tid & 15;
    float u2 = 0.f, v2 = 0.f, ur2 = 0.f, vr2 = 0.f;
    unsigned olo = 0u, ohi = 0u;

#pragma unroll
    for (int t = 0; t < 32; t++) {
        float c = 0.f;
#pragma unroll
        for (int i = 0; i < 3; i++) {
            const unsigned w = rowT[(row + i) * TP + t];
            c += lut[i * 8 + ((w >> col) & 7)];
        }
        v2 = D2 * (v2 + u2);
        float p = CP2 * v2;
        u2 = D2 * u2 + c;
        vr2 = DR2 * (vr2 + ur2);
        float m = p + CR2 * vr2;
        bool sp = (m >= TH2);
        ur2 = DR2 * ur2 + (sp ? 1.f : 0.f);
        olo |= sp ? (1u << t) : 0u;
    }
#pragma unroll
    for (int t = 0; t < 32; t++) {
        float c = 0.f;
#pragma unroll
        for (int i = 0; i < 3; i++) {
            const unsigned w = rowT[(row + i) * TP + (t + 32)];
            c += lut[i * 8 + ((w >> col) & 7)];
        }
        v2 = D2 * (v2 + u2);
        float p = CP2 * v2;
        u2 = D2 * u2 + c;
        vr2 = DR2 * (vr2 + ur2);
        float m = p + CR2 * vr2;
        bool sp = (m >= TH2);
        ur2 = DR2 * ur2 + (sp ? 1.f : 0.f);
        ohi |= sp ? (1u << t) : 0u;
    }
    s2b[tid] = make_uint2(olo, ohi);
    __syncthreads();

    // Output transpose: lanes = t, fully coalesced 256B float stores.
    for (int p = wv * 64; p < wv * 64 + 64; p++) {
        const uint2 b = s2b[p];                              // broadcast read
        const unsigned w = (ln < 32) ? b.x : b.y;
        const float v = (float)((w >> (ln & 31)) & 1u);
        const int prow = p >> 4, pcol = p & 15;
        out[(((size_t)n * HH + (y0 + prow)) * WW + (x0 + pcol)) * TT + ln] = v;
    }
}

extern "C" void kernel_launch(void* const* d_in, const int* in_sizes, int n_in,
                              void* d_out, int out_size, void* d_ws, size_t ws_size,
                              hipStream_t stream) {
    const float* in = (const float*)d_in[0];   // (4,1,192,192,64) f32 spikes
    const float* w1 = (const float*)d_in[1];   // (1,1,5,5)
    const float* w2 = (const float*)d_in[2];   // (1,1,3,3)
    float* out = (float*)d_out;                // (4,1,192,192,64) f32 spikes
    uint2* s1b = (uint2*)d_ws;                 // 4*192*192*8 B = 1.18 MB scratch

    dim3 grid(WW / TILE, HH / TILE, NIMG);     // 12 x 12 x 4 = 576 blocks
    k1_conv_lif<<<grid, NT, 0, stream>>>(in, w1, s1b);
    k2_conv_lif_out<<<grid, NT, 0, stream>>>(s1b, w2, out);
}

// Round 3
// 161.877 us; speedup vs baseline: 1.0552x; 1.0552x over previous
//
#include <hip/hip_runtime.h>

// SLAYER 2-layer SNN, MI355X. Round-3: row-LUT binary conv + EXPLICIT ILP.
// psp (temporal LTI, pointwise in space) commutes with conv2d (spatial,
// pointwise in time) -> both convs see BINARY spike trains.
//   K1: conv1(5x5) via 5-bit row-pattern LUT + psp1 + lif1 -> packed s1 (d_ws)
//   K2: conv2(3x3) via 3-bit row-pattern LUT + psp2 + lif2 -> float spikes
// rowT[r][t] (uint32): bit c = spike at column (x0-pad+c), time t.
// Round-2 lesson: inline LUT chain serialized (VGPR=24, VALUBusy 10%).
// Fix: per 8-t chunk, bulk ds_read_b128 the words, issue all 40 (K1) / 24 (K2)
// independent LUT gathers, THEN scan. launch_bounds(.,1) frees registers.
// Scan arithmetic is op-for-op identical to rounds 0-2 (absmax == 0).

#define HH   192
#define WW   192
#define NIMG 4
#define TT   64
#define TILE 16
#define NT   256
#define R1   20   // input rows/cols per tile for conv1 (pad 2)
#define R2   18   // s1 rows/cols per tile for conv2 (pad 1)

#define E_D 2.718281828459045
static constexpr float D1  = (float)0.36787944117144233;   // exp(-1/1)
static constexpr float CP1 = (float)(E_D);
static constexpr float DR1 = (float)0.36787944117144233;
static constexpr float CR1 = (float)(-30.0 * E_D);
static constexpr float D2  = (float)0.6065306597126334;    // exp(-1/2)
static constexpr float CP2 = (float)(E_D * 0.5);
static constexpr float DR2 = (float)0.6065306597126334;
static constexpr float CR2 = (float)(-50.0 * E_D * 0.5);
static constexpr float TH1 = 30.0f;
static constexpr float TH2 = 50.0f;

// ---------------- K1: conv1 (LUT) + psp1 + lif1 -> s1 packed bits ----------
__global__ __launch_bounds__(NT, 1)
void k1_conv_lif(const float* __restrict__ in, const float* __restrict__ w1g,
                 uint2* __restrict__ s1b) {
    __shared__ float    lut[5 * 32];
    __shared__ unsigned rowT[R1 * TT];     // 16B-aligned rows (stride 64 words)

    const int n = blockIdx.z, y0 = blockIdx.y * TILE, x0 = blockIdx.x * TILE;
    const int tid = threadIdx.x;

    if (tid < 160) {
        const int r = tid >> 5, p = tid & 31;
        float s = 0.f;
#pragma unroll
        for (int j = 0; j < 5; j++)
            if ((p >> j) & 1) s += w1g[r * 5 + j];
        lut[tid] = s;
    }

    // rowT build: lanes = t, wave wv handles rows wv, wv+4, ... (5 each).
    const int wv = tid >> 6, ln = tid & 63;
    for (int r = wv; r < R1; r += 4) {
        const int gy = y0 - 2 + r;
        unsigned word = 0u;
        if (gy >= 0 && gy < HH) {
            const float* rowp = in + (((size_t)n * HH + gy) * WW) * TT + ln;
#pragma unroll
            for (int c = 0; c < R1; c++) {
                const int gx = x0 - 2 + c;
                if (gx >= 0 && gx < WW) {
                    float v = rowp[(size_t)gx * TT];
                    word |= (v != 0.f) ? (1u << c) : 0u;
                }
            }
        }
        rowT[r * TT + ln] = word;
    }
    __syncthreads();

    // conv + scan, lane = output pixel (row = tid/16, col = tid%16)
    const int row = tid >> 4, col = tid & 15;
    float u1 = 0.f, v1 = 0.f, ur = 0.f, vr = 0.f;
    unsigned slo = 0u, shi = 0u;

#pragma unroll
    for (int tc = 0; tc < TT; tc += 8) {
        // stage 1: bulk-load 5 rows x 8 t words (10 x ds_read_b128)
        uint4 wa[5], wb[5];
#pragma unroll
        for (int i = 0; i < 5; i++) {
            const uint4* rp =
                reinterpret_cast<const uint4*>(&rowT[(row + i) * TT + tc]);
            wa[i] = rp[0];
            wb[i] = rp[1];
        }
        // stage 2: 40 independent LUT gathers
        float l[40];
#pragma unroll
        for (int i = 0; i < 5; i++) {
            const unsigned q[8] = {wa[i].x, wa[i].y, wa[i].z, wa[i].w,
                                   wb[i].x, wb[i].y, wb[i].z, wb[i].w};
#pragma unroll
            for (int j = 0; j < 8; j++)
                l[i * 8 + j] = lut[i * 32 + ((q[j] >> col) & 31)];
        }
        // stage 3: 8 sequential scan steps (op-identical to round-0)
#pragma unroll
        for (int j = 0; j < 8; j++) {
            const float c =
                ((l[0 * 8 + j] + l[1 * 8 + j]) + (l[2 * 8 + j] + l[3 * 8 + j]))
                + l[4 * 8 + j];
            v1 = D1 * (v1 + u1);
            const float p = CP1 * v1;
            u1 = D1 * u1 + c;
            vr = DR1 * (vr + ur);
            const float m = p + CR1 * vr;
            const bool sp = (m >= TH1);
            ur = DR1 * ur + (sp ? 1.f : 0.f);
            const unsigned bit = sp ? (1u << ((tc + j) & 31)) : 0u;
            if (tc < 32) slo |= bit;
            else         shi |= bit;
        }
    }
    s1b[((size_t)n * HH + (y0 + row)) * WW + (x0 + col)] = make_uint2(slo, shi);
}

// ---------------- K2: conv2 (LUT) + psp2 + lif2 -> float spikes ------------
__global__ __launch_bounds__(NT, 1)
void k2_conv_lif_out(const uint2* __restrict__ s1b, const float* __restrict__ w2g,
                     float* __restrict__ out) {
    __shared__ float    lut[3 * 8];
    __shared__ unsigned rowT[R2 * TT];
    __shared__ uint2    s2b[NT];

    const int n = blockIdx.z, y0 = blockIdx.y * TILE, x0 = blockIdx.x * TILE;
    const int tid = threadIdx.x;

    if (tid < 24) {
        const int r = tid >> 3, p = tid & 7;
        float s = 0.f;
#pragma unroll
        for (int j = 0; j < 3; j++)
            if ((p >> j) & 1) s += w2g[r * 3 + j];
        lut[tid] = s;
    }

    // rowT build from packed s1 bits: lanes = t, per-col word is wave-uniform.
    const int wv = tid >> 6, ln = tid & 63;
    for (int r = wv; r < R2; r += 4) {
        const int gy = y0 - 1 + r;
        unsigned word = 0u;
        if (gy >= 0 && gy < HH) {
            const uint2* rp = s1b + ((size_t)n * HH + gy) * WW;
#pragma unroll
            for (int c = 0; c < R2; c++) {
                const int gx = x0 - 1 + c;
                if (gx >= 0 && gx < WW) {
                    const uint2 b = rp[gx];               // uniform -> scalar
                    const unsigned w = (ln < 32) ? b.x : b.y;
                    word |= ((w >> (ln & 31)) & 1u) << c;
                }
            }
        }
        rowT[r * TT + ln] = word;
    }
    __syncthreads();

    const int row = tid >> 4, col = tid & 15;
    float u2 = 0.f, v2 = 0.f, ur2 = 0.f, vr2 = 0.f;
    unsigned olo = 0u, ohi = 0u;

#pragma unroll
    for (int tc = 0; tc < TT; tc += 8) {
        uint4 wa[3], wb[3];
#pragma unroll
        for (int i = 0; i < 3; i++) {
            const uint4* rp =
                reinterpret_cast<const uint4*>(&rowT[(row + i) * TT + tc]);
            wa[i] = rp[0];
            wb[i] = rp[1];
        }
        float l[24];
#pragma unroll
        for (int i = 0; i < 3; i++) {
            const unsigned q[8] = {wa[i].x, wa[i].y, wa[i].z, wa[i].w,
                                   wb[i].x, wb[i].y, wb[i].z, wb[i].w};
#pragma unroll
            for (int j = 0; j < 8; j++)
                l[i * 8 + j] = lut[i * 8 + ((q[j] >> col) & 7)];
        }
#pragma unroll
        for (int j = 0; j < 8; j++) {
            const float c = (l[0 * 8 + j] + l[1 * 8 + j]) + l[2 * 8 + j];
            v2 = D2 * (v2 + u2);
            const float p = CP2 * v2;
            u2 = D2 * u2 + c;
            vr2 = DR2 * (vr2 + ur2);
            const float m = p + CR2 * vr2;
            const bool sp = (m >= TH2);
            ur2 = DR2 * ur2 + (sp ? 1.f : 0.f);
            const unsigned bit = sp ? (1u << ((tc + j) & 31)) : 0u;
            if (tc < 32) olo |= bit;
            else         ohi |= bit;
        }
    }
    s2b[tid] = make_uint2(olo, ohi);
    __syncthreads();

    // Output transpose: lanes = t, coalesced 256B float stores.
    for (int p = wv * 64; p < wv * 64 + 64; p++) {
        const uint2 b = s2b[p];                            // broadcast read
        const unsigned w = (ln < 32) ? b.x : b.y;
        const float v = (float)((w >> (ln & 31)) & 1u);
        const int prow = p >> 4, pcol = p & 15;
        out[(((size_t)n * HH + (y0 + prow)) * WW + (x0 + pcol)) * TT + ln] = v;
    }
}

extern "C" void kernel_launch(void* const* d_in, const int* in_sizes, int n_in,
                              void* d_out, int out_size, void* d_ws, size_t ws_size,
                              hipStream_t stream) {
    const float* in = (const float*)d_in[0];   // (4,1,192,192,64) f32 spikes
    const float* w1 = (const float*)d_in[1];   // (1,1,5,5)
    const float* w2 = (const float*)d_in[2];   // (1,1,3,3)
    float* out = (float*)d_out;                // (4,1,192,192,64) f32 spikes
    uint2* s1b = (uint2*)d_ws;                 // 4*192*192*8 B = 1.18 MB scratch

    dim3 grid(WW / TILE, HH / TILE, NIMG);     // 12 x 12 x 4 = 576 blocks
    k1_conv_lif<<<grid, NT, 0, stream>>>(in, w1, s1b);
    k2_conv_lif_out<<<grid, NT, 0, stream>>>(s1b, w2, out);
}

// Round 4
// 145.463 us; speedup vs baseline: 1.1743x; 1.1128x over previous
//
#include <hip/hip_runtime.h>

// SLAYER 2-layer SNN, MI355X. Round-4: decouple streaming from scanning.
// psp (temporal LTI, pointwise in space) commutes with conv2d (spatial,
// pointwise in time) -> both convs see BINARY spike trains.
//   KA : floats -> packed bits (ballot), massively parallel streaming
//   KB : conv1(5x5, row-LUT) + psp1 + lif1 on L2-resident bits -> s1 bits
//   KC1: conv2(3x3, row-LUT) + psp2 + lif2 -> s2 bits (needs s1 halo)
//   KC2: s2 bits -> float spikes, massively parallel streaming stores
// Scan arithmetic is op-for-op identical to rounds 0-3 (absmax == 0 each time).

#define HH   192
#define WW   192
#define NIMG 4
#define TT   64
#define TILE 16
#define NT   256
#define R1   20            // input rows/cols per tile for conv1 (pad 2)
#define R2   18            // s1 rows/cols per tile for conv2 (pad 1)
#define PX   (NIMG * HH * WW)   // 147456 pixels
#define SBLK 2304          // streaming blocks: 9216 waves x 16 px = PX

#define E_D 2.718281828459045
static constexpr float D1  = (float)0.36787944117144233;   // exp(-1/1)
static constexpr float CP1 = (float)(E_D);
static constexpr float DR1 = (float)0.36787944117144233;
static constexpr float CR1 = (float)(-30.0 * E_D);
static constexpr float D2  = (float)0.6065306597126334;    // exp(-1/2)
static constexpr float CP2 = (float)(E_D * 0.5);
static constexpr float DR2 = (float)0.6065306597126334;
static constexpr float CR2 = (float)(-50.0 * E_D * 0.5);
static constexpr float TH1 = 30.0f;
static constexpr float TH2 = 50.0f;

// ---------------- KA: float spikes -> packed bits (t-major, bit t) ---------
__global__ __launch_bounds__(NT)
void ka_pack(const float* __restrict__ in, uint2* __restrict__ ibits) {
    const int gw = blockIdx.x * (NT / 64) + (threadIdx.x >> 6);  // global wave
    const int ln = threadIdx.x & 63;
    const int p0 = gw * 16;
#pragma unroll
    for (int k = 0; k < 16; k += 4) {
        const float v0 = in[(size_t)(p0 + k + 0) * TT + ln];
        const float v1 = in[(size_t)(p0 + k + 1) * TT + ln];
        const float v2 = in[(size_t)(p0 + k + 2) * TT + ln];
        const float v3 = in[(size_t)(p0 + k + 3) * TT + ln];
        const unsigned long long b0 = __ballot(v0 != 0.f);
        const unsigned long long b1 = __ballot(v1 != 0.f);
        const unsigned long long b2 = __ballot(v2 != 0.f);
        const unsigned long long b3 = __ballot(v3 != 0.f);
        if (ln == 0) {
            ibits[p0 + k + 0] = make_uint2((unsigned)b0, (unsigned)(b0 >> 32));
            ibits[p0 + k + 1] = make_uint2((unsigned)b1, (unsigned)(b1 >> 32));
            ibits[p0 + k + 2] = make_uint2((unsigned)b2, (unsigned)(b2 >> 32));
            ibits[p0 + k + 3] = make_uint2((unsigned)b3, (unsigned)(b3 >> 32));
        }
    }
}

// ---------------- KB: conv1 (LUT) + psp1 + lif1 -> s1 packed bits ----------
__global__ __launch_bounds__(NT, 1)
void kb_conv1(const uint2* __restrict__ ibits, const float* __restrict__ w1g,
              uint2* __restrict__ s1b) {
    __shared__ float    lut[5 * 32];
    __shared__ unsigned rowT[R1 * TT];

    const int n = blockIdx.z, y0 = blockIdx.y * TILE, x0 = blockIdx.x * TILE;
    const int tid = threadIdx.x;

    if (tid < 160) {
        const int r = tid >> 5, p = tid & 31;
        float s = 0.f;
#pragma unroll
        for (int j = 0; j < 5; j++)
            if ((p >> j) & 1) s += w1g[r * 5 + j];
        lut[tid] = s;
    }

    // rowT build from packed input bits; per-(r,c) words are wave-uniform.
    const int wv = tid >> 6, ln = tid & 63;
    for (int r = wv; r < R1; r += 4) {
        const int gy = y0 - 2 + r;
        unsigned word = 0u;
        if (gy >= 0 && gy < HH) {
            const uint2* rp = ibits + (size_t)(n * HH + gy) * WW;
#pragma unroll
            for (int c = 0; c < R1; c++) {
                const int gx = x0 - 2 + c;
                if (gx >= 0 && gx < WW) {
                    const uint2 b = rp[gx];                // uniform -> s_load
                    const unsigned w = (ln < 32) ? b.x : b.y;
                    word |= ((w >> (ln & 31)) & 1u) << c;
                }
            }
        }
        rowT[r * TT + ln] = word;
    }
    __syncthreads();

    const int row = tid >> 4, col = tid & 15;
    float u1 = 0.f, v1 = 0.f, ur = 0.f, vr = 0.f;
    unsigned slo = 0u, shi = 0u;

#pragma unroll
    for (int tc = 0; tc < TT; tc += 8) {
        uint4 wa[5], wb[5];
#pragma unroll
        for (int i = 0; i < 5; i++) {
            const uint4* rp =
                reinterpret_cast<const uint4*>(&rowT[(row + i) * TT + tc]);
            wa[i] = rp[0];
            wb[i] = rp[1];
        }
        float l[40];
#pragma unroll
        for (int i = 0; i < 5; i++) {
            const unsigned q[8] = {wa[i].x, wa[i].y, wa[i].z, wa[i].w,
                                   wb[i].x, wb[i].y, wb[i].z, wb[i].w};
#pragma unroll
            for (int j = 0; j < 8; j++)
                l[i * 8 + j] = lut[i * 32 + ((q[j] >> col) & 31)];
        }
#pragma unroll
        for (int j = 0; j < 8; j++) {
            const float c =
                ((l[0 * 8 + j] + l[1 * 8 + j]) + (l[2 * 8 + j] + l[3 * 8 + j]))
                + l[4 * 8 + j];
            v1 = D1 * (v1 + u1);
            const float p = CP1 * v1;
            u1 = D1 * u1 + c;
            vr = DR1 * (vr + ur);
            const float m = p + CR1 * vr;
            const bool sp = (m >= TH1);
            ur = DR1 * ur + (sp ? 1.f : 0.f);
            const unsigned bit = sp ? (1u << ((tc + j) & 31)) : 0u;
            if (tc < 32) slo |= bit;
            else         shi |= bit;
        }
    }
    s1b[((size_t)n * HH + (y0 + row)) * WW + (x0 + col)] = make_uint2(slo, shi);
}

// ---------------- KC1: conv2 (LUT) + psp2 + lif2 -> s2 packed bits ---------
__global__ __launch_bounds__(NT, 1)
void kc1_conv2(const uint2* __restrict__ s1b, const float* __restrict__ w2g,
               uint2* __restrict__ s2b) {
    __shared__ float    lut[3 * 8];
    __shared__ unsigned rowT[R2 * TT];

    const int n = blockIdx.z, y0 = blockIdx.y * TILE, x0 = blockIdx.x * TILE;
    const int tid = threadIdx.x;

    if (tid < 24) {
        const int r = tid >> 3, p = tid & 7;
        float s = 0.f;
#pragma unroll
        for (int j = 0; j < 3; j++)
            if ((p >> j) & 1) s += w2g[r * 3 + j];
        lut[tid] = s;
    }

    const int wv = tid >> 6, ln = tid & 63;
    for (int r = wv; r < R2; r += 4) {
        const int gy = y0 - 1 + r;
        unsigned word = 0u;
        if (gy >= 0 && gy < HH) {
            const uint2* rp = s1b + (size_t)(n * HH + gy) * WW;
#pragma unroll
            for (int c = 0; c < R2; c++) {
                const int gx = x0 - 1 + c;
                if (gx >= 0 && gx < WW) {
                    const uint2 b = rp[gx];                // uniform -> s_load
                    const unsigned w = (ln < 32) ? b.x : b.y;
                    word |= ((w >> (ln & 31)) & 1u) << c;
                }
            }
        }
        rowT[r * TT + ln] = word;
    }
    __syncthreads();

    const int row = tid >> 4, col = tid & 15;
    float u2 = 0.f, v2 = 0.f, ur2 = 0.f, vr2 = 0.f;
    unsigned olo = 0u, ohi = 0u;

#pragma unroll
    for (int tc = 0; tc < TT; tc += 8) {
        uint4 wa[3], wb[3];
#pragma unroll
        for (int i = 0; i < 3; i++) {
            const uint4* rp =
                reinterpret_cast<const uint4*>(&rowT[(row + i) * TT + tc]);
            wa[i] = rp[0];
            wb[i] = rp[1];
        }
        float l[24];
#pragma unroll
        for (int i = 0; i < 3; i++) {
            const unsigned q[8] = {wa[i].x, wa[i].y, wa[i].z, wa[i].w,
                                   wb[i].x, wb[i].y, wb[i].z, wb[i].w};
#pragma unroll
            for (int j = 0; j < 8; j++)
                l[i * 8 + j] = lut[i * 8 + ((q[j] >> col) & 7)];
        }
#pragma unroll
        for (int j = 0; j < 8; j++) {
            const float c = (l[0 * 8 + j] + l[1 * 8 + j]) + l[2 * 8 + j];
            v2 = D2 * (v2 + u2);
            const float p = CP2 * v2;
            u2 = D2 * u2 + c;
            vr2 = DR2 * (vr2 + ur2);
            const float m = p + CR2 * vr2;
            const bool sp = (m >= TH2);
            ur2 = DR2 * ur2 + (sp ? 1.f : 0.f);
            const unsigned bit = sp ? (1u << ((tc + j) & 31)) : 0u;
            if (tc < 32) olo |= bit;
            else         ohi |= bit;
        }
    }
    s2b[((size_t)n * HH + (y0 + row)) * WW + (x0 + col)] = make_uint2(olo, ohi);
}

// ---------------- KC2: packed s2 bits -> float spikes (streaming) ----------
__global__ __launch_bounds__(NT)
void kc2_unpack(const uint2* __restrict__ s2b, float* __restrict__ out) {
    const int gw = blockIdx.x * (NT / 64) + (threadIdx.x >> 6);
    const int ln = threadIdx.x & 63;
    const int p0 = gw * 16;
    const int sh = ln & 31;
#pragma unroll
    for (int k = 0; k < 16; k += 4) {
        const uint2 b0 = s2b[p0 + k + 0];
        const uint2 b1 = s2b[p0 + k + 1];
        const uint2 b2 = s2b[p0 + k + 2];
        const uint2 b3 = s2b[p0 + k + 3];
        const unsigned w0 = (ln < 32) ? b0.x : b0.y;
        const unsigned w1 = (ln < 32) ? b1.x : b1.y;
        const unsigned w2 = (ln < 32) ? b2.x : b2.y;
        const unsigned w3 = (ln < 32) ? b3.x : b3.y;
        out[(size_t)(p0 + k + 0) * TT + ln] = (float)((w0 >> sh) & 1u);
        out[(size_t)(p0 + k + 1) * TT + ln] = (float)((w1 >> sh) & 1u);
        out[(size_t)(p0 + k + 2) * TT + ln] = (float)((w2 >> sh) & 1u);
        out[(size_t)(p0 + k + 3) * TT + ln] = (float)((w3 >> sh) & 1u);
    }
}

extern "C" void kernel_launch(void* const* d_in, const int* in_sizes, int n_in,
                              void* d_out, int out_size, void* d_ws, size_t ws_size,
                              hipStream_t stream) {
    const float* in = (const float*)d_in[0];   // (4,1,192,192,64) f32 spikes
    const float* w1 = (const float*)d_in[1];   // (1,1,5,5)
    const float* w2 = (const float*)d_in[2];   // (1,1,3,3)
    float* out = (float*)d_out;                // (4,1,192,192,64) f32 spikes

    char* ws = (char*)d_ws;                    // 3 x 1.18 MB packed-bit planes
    uint2* ibits = (uint2*)(ws);
    uint2* s1b   = (uint2*)(ws + ((size_t)PX * 8 + 1024));
    uint2* s2b   = (uint2*)(ws + 2 * ((size_t)PX * 8 + 1024));

    dim3 tgrid(WW / TILE, HH / TILE, NIMG);    // 12 x 12 x 4 = 576 blocks
    ka_pack   <<<SBLK, NT, 0, stream>>>(in, ibits);
    kb_conv1  <<<tgrid, NT, 0, stream>>>(ibits, w1, s1b);
    kc1_conv2 <<<tgrid, NT, 0, stream>>>(s1b, w2, s2b);
    kc2_unpack<<<SBLK, NT, 0, stream>>>(s2b, out);
}

// Round 5
// 124.947 us; speedup vs baseline: 1.3671x; 1.1642x over previous
//
#include <hip/hip_runtime.h>

// SLAYER 2-layer SNN, MI355X. Round-5: structural ILP, registers over LDS.
// psp (temporal LTI, pointwise in space) commutes with conv2d (spatial,
// pointwise in time) -> both convs see BINARY spike trains.
//   KA: floats -> x-transposed bit words  bitT[y][xw][t] (uint32, bit = x%32)
//   KB: conv1(5x5, row-LUT from register bit-windows, lanes=t) -> ct[px][t]
//       -> scan (lanes=px) -> s1 as 16-bit x-halfwords s1h[y][xt][t]
//   KC: conv2(3x3) same structure -> scan -> in-kernel unpack to float out
// Scan arithmetic is op-for-op identical to rounds 0-4 (absmax == 0 each time).

#define HH   192
#define WW   192
#define NIMG 4
#define TT   64
#define TILE 16
#define NT   256
#define XW   6     // uint32 x-words per image row
#define XH   12    // 16-bit x-halfwords per image row

#define E_D 2.718281828459045
static constexpr float D1  = (float)0.36787944117144233;   // exp(-1/1)
static constexpr float CP1 = (float)(E_D);
static constexpr float DR1 = (float)0.36787944117144233;
static constexpr float CR1 = (float)(-30.0 * E_D);
static constexpr float D2  = (float)0.6065306597126334;    // exp(-1/2)
static constexpr float CP2 = (float)(E_D * 0.5);
static constexpr float DR2 = (float)0.6065306597126334;
static constexpr float CR2 = (float)(-50.0 * E_D * 0.5);
static constexpr float TH1 = 30.0f;
static constexpr float TH2 = 50.0f;

// ---------------- KA: float spikes -> x-transposed bit words ---------------
// wave = (image-row ny, x-word xw); lanes = t. No cross-lane ops needed:
// lane t accumulates its own 32 x-bits serially. Coalesced 256B loads.
__global__ __launch_bounds__(NT)
void ka_pack(const float* __restrict__ in, unsigned* __restrict__ bitT) {
    const int gw = blockIdx.x * (NT / 64) + (threadIdx.x >> 6);
    const int ln = threadIdx.x & 63;
    const int xw = gw % XW;
    const int ny = gw / XW;                 // n*HH + y
    const float* src = in + ((size_t)ny * WW + xw * 32) * TT + ln;
    unsigned w = 0u;
#pragma unroll
    for (int x = 0; x < 32; x++) {
        const float v = src[(size_t)x * TT];
        w |= (v != 0.f) ? (1u << x) : 0u;
    }
    bitT[((size_t)ny * XW + xw) * TT + ln] = w;
}

// ---------------- KB: conv1 + psp1 + lif1 -> s1 halfwords ------------------
__global__ __launch_bounds__(NT, 1)
void kb_layer1(const unsigned* __restrict__ bitT, const float* __restrict__ w1g,
               unsigned short* __restrict__ s1h) {
    __shared__ __align__(16) float ct[NT * 65];   // conv out [px][t], pad 65
    __shared__ float lut[5 * 32];

    const int n = blockIdx.z, ty = blockIdx.y, tx = blockIdx.x;
    const int y0 = ty * TILE, x0 = tx * TILE;
    const int tid = threadIdx.x;
    const int wv = tid >> 6, ln = tid & 63;

    // lut[r*32+p] = sum_j w1[r][j]*bit_j(p)  (same build as rounds 1-4)
    if (tid < 160) {
        const int r = tid >> 5, p = tid & 31;
        float s = 0.f;
#pragma unroll
        for (int j = 0; j < 5; j++)
            if ((p >> j) & 1) s += w1g[r * 5 + j];
        lut[tid] = s;
    }

    // Register bit-windows: w20[rr] bits c=0..19 <-> gx = x0-2+c, lane = t.
    // Window straddles 2 x-words; shift s in {14,30} (never 0 since x0%16==0).
    const int a = (x0 - 2) >> 5;
    const int s = (x0 - 2) & 31;
    unsigned w20[8];
#pragma unroll
    for (int rr = 0; rr < 8; rr++) {
        const int gy = y0 - 2 + wv * 4 + rr;
        unsigned wa = 0u, wb = 0u;
        if (gy >= 0 && gy < HH) {
            const unsigned* rp = bitT + ((size_t)(n * HH + gy) * XW) * TT + ln;
            if (a >= 0)     wa = rp[(size_t)a * TT];
            if (a + 1 < XW) wb = rp[(size_t)(a + 1) * TT];
        }
        w20[rr] = (wa >> s) | (wb << (32 - s));
    }
    __syncthreads();

    // Phase A: conv, lanes = t, 64 independent px streams per wave.
#pragma unroll
    for (int rp = 0; rp < 4; rp++) {
        const int row = wv * 4 + rp;
#pragma unroll
        for (int col = 0; col < 16; col++) {
            const float c =
                ((lut[  0 + ((w20[rp + 0] >> col) & 31)]
                + lut[ 32 + ((w20[rp + 1] >> col) & 31)])
                + (lut[ 64 + ((w20[rp + 2] >> col) & 31)]
                +  lut[ 96 + ((w20[rp + 3] >> col) & 31)]))
                +  lut[128 + ((w20[rp + 4] >> col) & 31)];
            ct[(row * 16 + col) * 65 + ln] = c;
        }
    }
    __syncthreads();

    // Phase B: scan, lane = px. Op-identical to rounds 0-4.
    unsigned slo = 0u, shi = 0u;
    {
        const int px = tid;
        float u1 = 0.f, v1 = 0.f, ur = 0.f, vr = 0.f;
#pragma unroll
        for (int tc = 0; tc < TT; tc += 8) {
            float c8[8];
#pragma unroll
            for (int j = 0; j < 8; j++) c8[j] = ct[px * 65 + tc + j];
#pragma unroll
            for (int j = 0; j < 8; j++) {
                v1 = D1 * (v1 + u1);
                const float p = CP1 * v1;
                u1 = D1 * u1 + c8[j];
                vr = DR1 * (vr + ur);
                const float m = p + CR1 * vr;
                const bool sp = (m >= TH1);
                ur = DR1 * ur + (sp ? 1.f : 0.f);
                const unsigned bit = sp ? (1u << ((tc + j) & 31)) : 0u;
                if (tc < 32) slo |= bit;
                else         shi |= bit;
            }
        }
    }
    __syncthreads();                       // all ct reads done
    ((uint2*)ct)[tid] = make_uint2(slo, shi);
    __syncthreads();

    // Phase T: emit 16-bit x-halfwords, lanes = t.
    const uint2* tb = (const uint2*)ct;
#pragma unroll
    for (int rp = 0; rp < 4; rp++) {
        const int yl = wv * 4 + rp;
        unsigned h = 0u;
#pragma unroll
        for (int x = 0; x < 16; x++) {
            const uint2 b = tb[yl * 16 + x];           // LDS broadcast
            const unsigned w = (ln < 32) ? b.x : b.y;
            h |= ((w >> (ln & 31)) & 1u) << x;
        }
        s1h[((size_t)(n * HH + y0 + yl) * XH + tx) * TT + ln] = (unsigned short)h;
    }
}

// ---------------- KC: conv2 + psp2 + lif2 -> float spikes ------------------
__global__ __launch_bounds__(NT, 1)
void kc_layer2(const unsigned short* __restrict__ s1h, const float* __restrict__ w2g,
               float* __restrict__ out) {
    __shared__ __align__(16) float ct[NT * 65];
    __shared__ float lut[3 * 8];

    const int n = blockIdx.z, ty = blockIdx.y, tx = blockIdx.x;
    const int y0 = ty * TILE, x0 = tx * TILE;
    const int tid = threadIdx.x;
    const int wv = tid >> 6, ln = tid & 63;

    if (tid < 24) {
        const int r = tid >> 3, p = tid & 7;
        float s = 0.f;
#pragma unroll
        for (int j = 0; j < 3; j++)
            if ((p >> j) & 1) s += w2g[r * 3 + j];
        lut[tid] = s;
    }

    // w18[rr] bits c=0..17 <-> gx = x0-1+c, from 3 s1 halfwords, lane = t.
    unsigned w18[6];
#pragma unroll
    for (int rr = 0; rr < 6; rr++) {
        const int gy = y0 - 1 + wv * 4 + rr;
        unsigned hm = 0u, h0 = 0u, hp = 0u;
        if (gy >= 0 && gy < HH) {
            const unsigned short* rp = s1h + ((size_t)(n * HH + gy) * XH) * TT + ln;
            if (tx > 0)      hm = rp[(size_t)(tx - 1) * TT];
            h0 = rp[(size_t)tx * TT];
            if (tx + 1 < XH) hp = rp[(size_t)(tx + 1) * TT];
        }
        w18[rr] = (hm >> 15) | (h0 << 1) | ((hp & 1u) << 17);
    }
    __syncthreads();

#pragma unroll
    for (int rp = 0; rp < 4; rp++) {
        const int row = wv * 4 + rp;
#pragma unroll
        for (int col = 0; col < 16; col++) {
            const float c =
                (lut[ 0 + ((w18[rp + 0] >> col) & 7)]
               + lut[ 8 + ((w18[rp + 1] >> col) & 7)])
               + lut[16 + ((w18[rp + 2] >> col) & 7)];
            ct[(row * 16 + col) * 65 + ln] = c;
        }
    }
    __syncthreads();

    unsigned olo = 0u, ohi = 0u;
    {
        const int px = tid;
        float u2 = 0.f, v2 = 0.f, ur2 = 0.f, vr2 = 0.f;
#pragma unroll
        for (int tc = 0; tc < TT; tc += 8) {
            float c8[8];
#pragma unroll
            for (int j = 0; j < 8; j++) c8[j] = ct[px * 65 + tc + j];
#pragma unroll
            for (int j = 0; j < 8; j++) {
                v2 = D2 * (v2 + u2);
                const float p = CP2 * v2;
                u2 = D2 * u2 + c8[j];
                vr2 = DR2 * (vr2 + ur2);
                const float m = p + CR2 * vr2;
                const bool sp = (m >= TH2);
                ur2 = DR2 * ur2 + (sp ? 1.f : 0.f);
                const unsigned bit = sp ? (1u << ((tc + j) & 31)) : 0u;
                if (tc < 32) olo |= bit;
                else         ohi |= bit;
            }
        }
    }
    __syncthreads();
    ((uint2*)ct)[tid] = make_uint2(olo, ohi);
    __syncthreads();

    // Phase C: unpack to float, lanes = t, coalesced 256B stores.
    const uint2* tb = (const uint2*)ct;
    const int sh = ln & 31;
#pragma unroll
    for (int k = 0; k < 64; k++) {
        const int p = wv * 64 + k;
        const uint2 b = tb[p];
        const unsigned w = (ln < 32) ? b.x : b.y;
        out[((size_t)(n * HH + y0 + (p >> 4)) * WW + x0 + (p & 15)) * TT + ln] =
            (float)((w >> sh) & 1u);
    }
}

extern "C" void kernel_launch(void* const* d_in, const int* in_sizes, int n_in,
                              void* d_out, int out_size, void* d_ws, size_t ws_size,
                              hipStream_t stream) {
    const float* in = (const float*)d_in[0];   // (4,1,192,192,64) f32 spikes
    const float* w1 = (const float*)d_in[1];   // (1,1,5,5)
    const float* w2 = (const float*)d_in[2];   // (1,1,3,3)
    float* out = (float*)d_out;                // (4,1,192,192,64) f32 spikes

    char* ws = (char*)d_ws;
    unsigned*       bitT = (unsigned*)ws;                  // 1.18 MB
    unsigned short* s1h  = (unsigned short*)(ws + (2u << 20));  // 1.18 MB

    const int ka_blocks = (NIMG * HH * XW) / (NT / 64);    // 4608 waves / 4
    dim3 tgrid(WW / TILE, HH / TILE, NIMG);                // 12 x 12 x 4
    ka_pack  <<<ka_blocks, NT, 0, stream>>>(in, bitT);
    kb_layer1<<<tgrid, NT, 0, stream>>>(bitT, w1, s1h);
    kc_layer2<<<tgrid, NT, 0, stream>>>(s1h, w2, out);
}